// Round 2
// baseline (700.603 us; speedup 1.0000x reference)
//
#include <hip/hip_runtime.h>
#include <hip/hip_bf16.h>

#define B_N 4096
#define L_N 50
#define D_N 64

// d_ws float layout (element offsets)
#define W1T 0        // [128][64]  w_r1 transposed
#define W2T 8192     // [64][64]   w_r2 transposed
#define A1T 12288    // [128][64]  att1_w transposed
#define A2T 20480    // [64][64]   att2_w transposed
#define W3  24576    // [64]       att3_w
#define B1  24640    // [64]
#define B2  24704    // [64]
#define AB1 24768    // [64]
#define AB2 24832    // [64]
#define FLAG 24896   // 1.0f if inputs are fp32, 0.0f if bf16
#define WS_FLOATS 24897   // 99,588 bytes needed in d_ws

__device__ __forceinline__ float bflo(unsigned p) { return __uint_as_float(p << 16); }
__device__ __forceinline__ float bfhi(unsigned p) { return __uint_as_float(p & 0xffff0000u); }
__device__ __forceinline__ float bf1(unsigned short u) { return __uint_as_float(((unsigned)u) << 16); }
__device__ __forceinline__ unsigned short f2bf(float f) {
    unsigned u = __float_as_uint(f);
    u += 0x7fffu + ((u >> 16) & 1u);   // round-to-nearest-even (finite values only)
    return (unsigned short)(u >> 16);
}
__device__ __forceinline__ unsigned packbf(float a, float b) {
    return (unsigned)f2bf(a) | ((unsigned)f2bf(b) << 16);
}
// read element i of a float tensor whose on-device dtype is fp32 (isf=1) or bf16 (isf=0)
__device__ __forceinline__ float rdv(const void* p, long i, int isf) {
    return isf ? ((const float*)p)[i] : bf1(((const unsigned short*)p)[i]);
}

// Detect dtype, then convert weights -> fp32 in ws, transposed so wT[i*64+e] = w[e][i].
__global__ void prep_kernel(const void* __restrict__ w1, const void* __restrict__ b1,
                            const void* __restrict__ w2, const void* __restrict__ b2,
                            const void* __restrict__ a1, const void* __restrict__ ab1,
                            const void* __restrict__ a2, const void* __restrict__ ab2,
                            const void* __restrict__ w3, float* __restrict__ W) {
    __shared__ int sfl;
    if (threadIdx.x == 0) {
        // Even-index shorts: if data is bf16 these ARE w_r1 values (all |v|<=0.089);
        // if data is fp32 they are low mantissa bits -> random bf16, ~49% in range.
        const unsigned short* s = (const unsigned short*)w1;
        int cnt = 0;
        for (int k = 0; k < 128; ++k) {
            float v = bf1(s[2 * k]);
            if (v == v && fabsf(v) <= 0.25f) ++cnt;
        }
        sfl = (cnt >= 100) ? 0 : 1;   // 0 = bf16, 1 = fp32
    }
    __syncthreads();
    const int isf = sfl;
    int t = blockIdx.x * 256 + threadIdx.x;
    if (t == 0) W[FLAG] = (float)isf;
    if (t < 8192) {                    // W1T
        int e = t & 63, i = t >> 6;
        W[W1T + t] = rdv(w1, e * 128 + i, isf);
    } else if (t < 12288) {            // W2T
        int q = t - 8192; int e = q & 63, i = q >> 6;
        W[W2T + q] = rdv(w2, e * 64 + i, isf);
    } else if (t < 20480) {            // A1T
        int q = t - 12288; int e = q & 63, i = q >> 6;
        W[A1T + q] = rdv(a1, e * 128 + i, isf);
    } else if (t < 24576) {            // A2T
        int q = t - 20480; int e = q & 63, i = q >> 6;
        W[A2T + q] = rdv(a2, e * 64 + i, isf);
    } else if (t < 24640) W[t] = rdv(w3, t - 24576, isf);
    else if (t < 24704) W[t] = rdv(b1, t - 24640, isf);
    else if (t < 24768) W[t] = rdv(b2, t - 24704, isf);
    else if (t < 24832) W[t] = rdv(ab1, t - 24768, isf);
    else if (t < FLAG)  W[t] = rdv(ab2, t - 24832, isf);
}

// One wave per batch row b; lane = history position l.
// Weights are wave-uniform -> s_load path; activations per-lane in LDS rows.
__launch_bounds__(64)
__global__ void agg_kernel(const int* __restrict__ nodes, const int* __restrict__ history,
                           const int* __restrict__ ratings, const int* __restrict__ lengths,
                           const void* __restrict__ u2e,
                           const void* __restrict__ r2e,
                           const void* __restrict__ rating2e,
                           const float* __restrict__ W,
                           void* __restrict__ out) {
    __shared__ unsigned xbuf[64 * 66];   // bf16-pair x rows; later reused as fp32 o rows
    __shared__ unsigned ybuf[64 * 34];   // bf16-pair y / a1 rows
    __shared__ float ur_s[64];
    __shared__ float c1_s[64];
    __shared__ float attw_s[64];

    const int b = blockIdx.x;
    const int l = threadIdx.x;
    const int lc = min(l, L_N - 1);
    const int node = nodes[b];
    const int lenb = lengths[b];
    const int isf = (W[FLAG] != 0.0f) ? 1 : 0;   // wave-uniform

    // user embedding row (uniform row, lane d=l loads one element)
    ur_s[l] = rdv(u2e, ((long)node << 6) + l, isf);

    // gather x = [r2e[hist], rating2e[rat]] as packed bf16 pairs into own LDS row
    {
        const int h = history[b * L_N + lc];
        const int r = ratings[b * L_N + lc];
        if (!isf) {
            const uint4* pu = (const uint4*)((const unsigned short*)r2e + ((long)h << 6));
            const uint4* pv = (const uint4*)((const unsigned short*)rating2e + ((long)r << 6));
#pragma unroll
            for (int k = 0; k < 8; ++k) {
                uint4 t = pu[k];
                *(uint2*)&xbuf[l * 66 + 4 * k] = make_uint2(t.x, t.y);
                *(uint2*)&xbuf[l * 66 + 4 * k + 2] = make_uint2(t.z, t.w);
            }
#pragma unroll
            for (int k = 0; k < 8; ++k) {
                uint4 t = pv[k];
                *(uint2*)&xbuf[l * 66 + 32 + 4 * k] = make_uint2(t.x, t.y);
                *(uint2*)&xbuf[l * 66 + 32 + 4 * k + 2] = make_uint2(t.z, t.w);
            }
        } else {
            const float4* pu = (const float4*)((const float*)r2e + ((long)h << 6));
            const float4* pv = (const float4*)((const float*)rating2e + ((long)r << 6));
#pragma unroll
            for (int k = 0; k < 16; ++k) {
                float4 t = pu[k];
                xbuf[l * 66 + 2 * k] = packbf(t.x, t.y);
                xbuf[l * 66 + 2 * k + 1] = packbf(t.z, t.w);
            }
#pragma unroll
            for (int k = 0; k < 16; ++k) {
                float4 t = pv[k];
                xbuf[l * 66 + 32 + 2 * k] = packbf(t.x, t.y);
                xbuf[l * 66 + 32 + 2 * k + 1] = packbf(t.z, t.w);
            }
        }
    }
    __syncthreads();

    // c1[e] = att1_b[e] + sum_i att1_w[e, 64+i] * ur[i]   (lane = e, once per block)
    {
        float a = W[AB1 + l];
#pragma unroll 4
        for (int i = 0; i < 64; ++i) a += W[A1T + (64 + i) * 64 + l] * ur_s[i];
        c1_s[l] = a;
    }
    __syncthreads();

    float acc[64];

    // ---- layer 1: x(128, bf16 pairs) -> y(64) ----
#pragma unroll
    for (int e = 0; e < 64; ++e) acc[e] = W[B1 + e];
#pragma unroll 2
    for (int i = 0; i < 64; ++i) {
        const unsigned p = xbuf[l * 66 + i];
        const float x0 = bflo(p), x1 = bfhi(p);
        const float* w0 = &W[W1T + (i * 2) * 64];
        const float* w1 = w0 + 64;
#pragma unroll
        for (int e = 0; e < 64; ++e) acc[e] += w0[e] * x0 + w1[e] * x1;
    }
#pragma unroll
    for (int e2 = 0; e2 < 32; ++e2)
        ybuf[l * 34 + e2] = packbf(fmaxf(acc[2 * e2], 0.f), fmaxf(acc[2 * e2 + 1], 0.f));

    // ---- layer 2: y(64) -> o(64) ----
#pragma unroll
    for (int e = 0; e < 64; ++e) acc[e] = W[B2 + e];
#pragma unroll 2
    for (int i = 0; i < 32; ++i) {
        const unsigned p = ybuf[l * 34 + i];
        const float x0 = bflo(p), x1 = bfhi(p);
        const float* w0 = &W[W2T + (i * 2) * 64];
        const float* w1 = w0 + 64;
#pragma unroll
        for (int e = 0; e < 64; ++e) acc[e] += w0[e] * x0 + w1[e] * x1;
    }
    float* ofp = (float*)xbuf;   // x row is dead for this lane; store o fp32 there
#pragma unroll
    for (int e = 0; e < 64; ++e) {
        acc[e] = fmaxf(acc[e], 0.f);
        ofp[l * 66 + e] = acc[e];
    }

    // ---- att1: a1 = relu(att1_w[:, :64] @ o + c1) ----
#pragma unroll
    for (int e = 0; e < 64; ++e) acc[e] = c1_s[e];
#pragma unroll 2
    for (int i = 0; i < 64; ++i) {
        const float xi = ofp[l * 66 + i];
        const float* w0 = &W[A1T + i * 64];
#pragma unroll
        for (int e = 0; e < 64; ++e) acc[e] += w0[e] * xi;
    }
#pragma unroll
    for (int e2 = 0; e2 < 32; ++e2)
        ybuf[l * 34 + e2] = packbf(fmaxf(acc[2 * e2], 0.f), fmaxf(acc[2 * e2 + 1], 0.f));

    // ---- att2 ----
#pragma unroll
    for (int e = 0; e < 64; ++e) acc[e] = W[AB2 + e];
#pragma unroll 2
    for (int i = 0; i < 32; ++i) {
        const unsigned p = ybuf[l * 34 + i];
        const float x0 = bflo(p), x1 = bfhi(p);
        const float* w0 = &W[A2T + (i * 2) * 64];
        const float* w1 = w0 + 64;
#pragma unroll
        for (int e = 0; e < 64; ++e) acc[e] += w0[e] * x0 + w1[e] * x1;
    }

    // ---- att3: score (att3_b cancels in softmax) ----
    float s0 = 0.f, s1 = 0.f, s2 = 0.f, s3 = 0.f;
#pragma unroll
    for (int e = 0; e < 64; e += 4) {
        s0 += fmaxf(acc[e], 0.f) * W[W3 + e];
        s1 += fmaxf(acc[e + 1], 0.f) * W[W3 + e + 1];
        s2 += fmaxf(acc[e + 2], 0.f) * W[W3 + e + 2];
        s3 += fmaxf(acc[e + 3], 0.f) * W[W3 + e + 3];
    }
    const float score = (s0 + s1) + (s2 + s3);

    // ---- masked softmax over lanes ----
    const bool valid = (l < lenb);   // lenb <= 50, so also masks l in [50,64)
    float mx = valid ? score : -1e30f;
#pragma unroll
    for (int m = 32; m > 0; m >>= 1) mx = fmaxf(mx, __shfl_xor(mx, m, 64));
    const float pw = valid ? __expf(score - mx) : 0.f;
    float sum = pw;
#pragma unroll
    for (int m = 32; m > 0; m >>= 1) sum += __shfl_xor(sum, m, 64);
    attw_s[l] = pw / sum;
    __syncthreads();

    // ---- out[b][d] = sum_l attw[l] * o[l][d]  (lane = d, transpose read) ----
    float od = 0.f;
#pragma unroll 2
    for (int j = 0; j < L_N; ++j) od += attw_s[j] * ofp[j * 66 + l];
    if (isf) ((float*)out)[((long)b << 6) + l] = od;
    else     ((unsigned short*)out)[((long)b << 6) + l] = f2bf(od);
}

extern "C" void kernel_launch(void* const* d_in, const int* in_sizes, int n_in,
                              void* d_out, int out_size, void* d_ws, size_t ws_size,
                              hipStream_t stream) {
    const int* nodes = (const int*)d_in[0];
    const int* history = (const int*)d_in[1];
    const int* ratings = (const int*)d_in[2];
    const int* lengths = (const int*)d_in[3];
    const void* u2e = d_in[4];
    const void* r2e = d_in[5];
    const void* rating2e = d_in[6];
    const void* w1 = d_in[7];
    const void* b1 = d_in[8];
    const void* w2 = d_in[9];
    const void* b2 = d_in[10];
    const void* a1 = d_in[11];
    const void* ab1 = d_in[12];
    const void* a2 = d_in[13];
    const void* ab2 = d_in[14];
    const void* w3 = d_in[15];
    // d_in[16] = att3_b: additive constant on pre-softmax scores -> cancels; unused.
    float* W = (float*)d_ws;   // needs 99,588 bytes

    prep_kernel<<<(WS_FLOATS + 255) / 256, 256, 0, stream>>>(w1, b1, w2, b2, a1, ab1, a2, ab2, w3, W);
    agg_kernel<<<B_N, 64, 0, stream>>>(nodes, history, ratings, lengths, u2e, r2e, rating2e, W, d_out);
}